// Round 8
// baseline (11.572 us; speedup 1.0000x reference)
//
#include <hip/hip_runtime.h>

#define B_ 2
#define L_ 2048
#define H_ 8
#define HD 64
#define K_ 63
#define TQ 64
#define NT (L_ / TQ)          // 32 query tiles per (b,h)
#define ROWS 128              // staged window union (126 used)
#define EXPC 0.1803368801111204f   // scale(=hd^-0.5=0.125) * log2(e)

typedef __attribute__((ext_vector_type(8))) short bf16x8;   // MFMA A/B operand
typedef __attribute__((ext_vector_type(4))) float f32x4;    // MFMA C/D operand

// packed f32x2 -> bf16x2 (RNE), single HW instruction on gfx950
__device__ inline unsigned cvt_pk_bf16(float lo, float hi) {
    unsigned r;
    asm("v_cvt_pk_bf16_f32 %0, %1, %2" : "=v"(r) : "v"(lo), "v"(hi));
    return r;
}
__device__ inline unsigned short f2bf(float f) {            // RNE scalar
    unsigned u = __float_as_uint(f);
    unsigned r = ((u >> 16) & 1u) + 0x7FFFu;
    return (unsigned short)((u + r) >> 16);
}
__device__ inline float bf2f(unsigned short s) {
    return __uint_as_float(((unsigned)s) << 16);
}

// Key-split flash design: 8 waves/block. Wave w: qg = w&3 (16 queries),
// half = w>>2 (0: band keys [wb,wb+64), 1: [wb+64,wb+96)). Each half does
// partial S^T / masked softmax (m_h, z_h) / partial PV; halves merge via
// exact flash combine in the epilogue (half0 waves).
//
// LDS (ushort idx, XOR-swizzled at 16B-group granularity):
//  kv [128 keys][64 d]   grp(8/row)  ^= (row&7)   (S^T frags; d-split A/B disjoint)
//  kvT[64 d][128 keys]   grp(16/row) ^= (d&15)    (PV B(V) frags)
//  pt [8 waves][16 q][64 k] grp ^= (q&7)          (PV A(P) frags, per-wave)
//    half1's pt region is reused (same wave, in-order) for its bf16 O-partial.
__global__ __launch_bounds__(512, 4) void natten1d_mfma(
    const float* __restrict__ x, float* __restrict__ out)
{
    __shared__ unsigned short kv_sh [ROWS * 64];    // 16 KB
    __shared__ unsigned short kvT_sh[64 * ROWS];    // 16 KB
    __shared__ unsigned short pt_sh [8 * 16 * 64];  // 16 KB
    __shared__ float2 mz0_sh[4][16];                // (m0,z0) per (qg, q)
    __shared__ float2 mz1_sh[4][16];                // (m1,z1) per (qg, q)

    // Bijective XCD-chunked swizzle (512 % 8 == 0)
    const int bid = blockIdx.x;
    const int wid = (bid & 7) * (B_ * H_ * NT / 8) + (bid >> 3);
    const int bh  = wid / NT;
    const int t   = wid % NT;
    const int b   = bh / H_;
    const int h   = bh % H_;
    const int l0  = t * TQ;
    const int key_base = min(max(l0 - K_ / 2, 0), L_ - K_);
    const int qoff     = l0 - key_base;          // 0 (first tile) or 31

    const int tid = threadIdx.x;
    const int c   = tid & 7;                     // d4 within d-half
    const int rw  = tid >> 3;                    // 0..63 -> rows 2rw, 2rw+1

    // ---- issue ALL global loads up front (A = d 0..31, B = d 32..63) ----
    const float4* xb = (const float4*)x + (size_t)b * (L_ * H_ * HD / 4) + h * (HD / 4);
    float4 la[2], lb[2];
    #pragma unroll
    for (int rr = 0; rr < 2; ++rr) {
        const int g = key_base + rw * 2 + rr;
        const bool ok = (g < L_);
        const size_t ro = (size_t)g * (H_ * HD / 4);
        la[rr] = ok ? xb[ro + c]     : make_float4(0.f, 0.f, 0.f, 0.f);
        lb[rr] = ok ? xb[ro + c + 8] : make_float4(0.f, 0.f, 0.f, 0.f);
    }

    // ---- stage half A ----
    #pragma unroll
    for (int rr = 0; rr < 2; ++rr) {
        const int r = rw * 2 + rr;
        uint2 w;
        w.x = cvt_pk_bf16(la[rr].x, la[rr].y);
        w.y = cvt_pk_bf16(la[rr].z, la[rr].w);
        *(uint2*)&kv_sh[r * 64 + (((c >> 1) ^ (r & 7)) << 3) + (c & 1) * 4] = w;
    }
    {
        const float* f0 = (const float*)&la[0];
        const float* f1 = (const float*)&la[1];
        #pragma unroll
        for (int e = 0; e < 4; ++e) {
            const int d = c * 4 + e;                 // 0..31
            *(unsigned*)&kvT_sh[d * 128 + (((rw >> 2) ^ (d & 15)) << 3) + ((rw & 3) << 1)]
                = cvt_pk_bf16(f0[e], f1[e]);
        }
    }
    __syncthreads();

    const int wave = tid >> 6;
    const int qg   = wave & 3;
    const int half = wave >> 2;
    const int lane = tid & 63;
    const int lq = lane & 15;
    const int lg = lane >> 4;

    const int q0    = qg * 16;
    const int soff0 = min(max(l0 + q0 - K_ / 2, 0), L_ - K_) - key_base;
    const int wb    = min(soff0 & ~15, ROWS - 96);   // 16-aligned band base
    const int qrow  = qoff + q0 + lq;
    const int soffq = min(max(l0 + q0 + lq - K_ / 2, 0), L_ - K_) - key_base;
    const int cbase = wb + lg * 4 - soffq;           // mask helper

    // ---- S^T chain-0 (d 0..31), per-half nb range ----
    f32x4 acc[4];
    #pragma unroll
    for (int nb = 0; nb < 4; ++nb) acc[nb] = (f32x4){0.f, 0.f, 0.f, 0.f};
    {
        const bf16x8 bq0 = *(const bf16x8*)&kv_sh[qrow * 64 + ((lg ^ (qrow & 7)) << 3)];
        if (half == 0) {
            #pragma unroll
            for (int nb = 0; nb < 4; ++nb) {
                const int krow = wb + nb * 16 + lq;
                const bf16x8 a0 = *(const bf16x8*)&kv_sh[krow * 64 + ((lg ^ (krow & 7)) << 3)];
                acc[nb] = __builtin_amdgcn_mfma_f32_16x16x32_bf16(a0, bq0, acc[nb], 0, 0, 0);
            }
        } else {
            #pragma unroll
            for (int nb = 0; nb < 2; ++nb) {
                const int krow = wb + (4 + nb) * 16 + lq;
                const bf16x8 a0 = *(const bf16x8*)&kv_sh[krow * 64 + ((lg ^ (krow & 7)) << 3)];
                acc[nb] = __builtin_amdgcn_mfma_f32_16x16x32_bf16(a0, bq0, acc[nb], 0, 0, 0);
            }
        }
    }

    // ---- stage half B (disjoint slots; loads drained under chain-0) ----
    #pragma unroll
    for (int rr = 0; rr < 2; ++rr) {
        const int r = rw * 2 + rr;
        uint2 w;
        w.x = cvt_pk_bf16(lb[rr].x, lb[rr].y);
        w.y = cvt_pk_bf16(lb[rr].z, lb[rr].w);
        *(uint2*)&kv_sh[r * 64 + ((((c >> 1) + 4) ^ (r & 7)) << 3) + (c & 1) * 4] = w;
    }
    {
        const float* f0 = (const float*)&lb[0];
        const float* f1 = (const float*)&lb[1];
        #pragma unroll
        for (int e = 0; e < 4; ++e) {
            const int d = 32 + c * 4 + e;            // 32..63
            *(unsigned*)&kvT_sh[d * 128 + (((rw >> 2) ^ (d & 15)) << 3) + ((rw & 3) << 1)]
                = cvt_pk_bf16(f0[e], f1[e]);
        }
    }
    __syncthreads();

    // ---- S^T chain-1 (d 32..63) ----
    {
        const bf16x8 bq1 = *(const bf16x8*)&kv_sh[qrow * 64 + (((4 + lg) ^ (qrow & 7)) << 3)];
        if (half == 0) {
            #pragma unroll
            for (int nb = 0; nb < 4; ++nb) {
                const int krow = wb + nb * 16 + lq;
                const bf16x8 a1 = *(const bf16x8*)&kv_sh[krow * 64 + (((4 + lg) ^ (krow & 7)) << 3)];
                acc[nb] = __builtin_amdgcn_mfma_f32_16x16x32_bf16(a1, bq1, acc[nb], 0, 0, 0);
            }
        } else {
            #pragma unroll
            for (int nb = 0; nb < 2; ++nb) {
                const int krow = wb + (4 + nb) * 16 + lq;
                const bf16x8 a1 = *(const bf16x8*)&kv_sh[krow * 64 + (((4 + lg) ^ (krow & 7)) << 3)];
                acc[nb] = __builtin_amdgcn_mfma_f32_16x16x32_bf16(a1, bq1, acc[nb], 0, 0, 0);
            }
        }
    }

    // ---- per-lane masked partial softmax over this half's cols ----
    const int NBH = (half == 0) ? 4 : 2;
    float mx = -1e30f;
    #pragma unroll
    for (int nb = 0; nb < 4; ++nb) {
        if (nb >= NBH) break;
        const int nbg = half * 4 + nb;
        #pragma unroll
        for (int r = 0; r < 4; ++r) {
            const bool valid = (unsigned)(cbase + nbg * 16 + r) < (unsigned)K_;
            const float s = valid ? acc[nb][r] : -1e30f;
            acc[nb][r] = s;
            mx = fmaxf(mx, s);
        }
    }
    mx = fmaxf(mx, __shfl_xor(mx, 16));
    mx = fmaxf(mx, __shfl_xor(mx, 32));
    float z = 0.f;
    #pragma unroll
    for (int nb = 0; nb < 4; ++nb) {
        if (nb >= NBH) break;
        #pragma unroll
        for (int r = 0; r < 4; ++r) {
            const float e = exp2f((acc[nb][r] - mx) * EXPC);
            acc[nb][r] = e;                          // unnormalized partial P
            z += e;
        }
    }
    z += __shfl_xor(z, 16);
    z += __shfl_xor(z, 32);

    // ---- publish (m_h, z_h) per query ----
    if (lg == 0) {
        if (half == 0) mz0_sh[qg][lq] = make_float2(mx, z);
        else           mz1_sh[qg][lq] = make_float2(mx, z);
    }

    // ---- P -> per-wave pt tile (uint2; local keys nb*16 + lg*4 + 0..3) ----
    unsigned short* ptw = &pt_sh[wave * 16 * 64];
    #pragma unroll
    for (int nb = 0; nb < 4; ++nb) {
        if (nb >= NBH) break;
        uint2 w;
        w.x = cvt_pk_bf16(acc[nb][0], acc[nb][1]);
        w.y = cvt_pk_bf16(acc[nb][2], acc[nb][3]);
        const int g = nb * 2 + (lg >> 1);
        *(uint2*)&ptw[lq * 64 + ((g ^ (lq & 7)) << 3) + ((lg & 1) << 2)] = w;
    }

    // ---- partial O = P * V over this half's keys ----
    f32x4 o4[4];
    #pragma unroll
    for (int nb2 = 0; nb2 < 4; ++nb2) o4[nb2] = (f32x4){0.f, 0.f, 0.f, 0.f};
    if (half == 0) {
        bf16x8 ap0 = *(const bf16x8*)&ptw[lq * 64 + (((0 * 4 + lg) ^ (lq & 7)) << 3)];
        bf16x8 ap1 = *(const bf16x8*)&ptw[lq * 64 + (((1 * 4 + lg) ^ (lq & 7)) << 3)];
        #pragma unroll
        for (int nb2 = 0; nb2 < 4; ++nb2) {
            const int d = nb2 * 16 + lq;
            const int g0 = ((wb >> 3) + lg)     ^ (d & 15);
            const int g1 = ((wb >> 3) + 4 + lg) ^ (d & 15);
            const bf16x8 bv0 = *(const bf16x8*)&kvT_sh[d * 128 + (g0 << 3)];
            const bf16x8 bv1 = *(const bf16x8*)&kvT_sh[d * 128 + (g1 << 3)];
            o4[nb2] = __builtin_amdgcn_mfma_f32_16x16x32_bf16(ap0, bv0, o4[nb2], 0, 0, 0);
            o4[nb2] = __builtin_amdgcn_mfma_f32_16x16x32_bf16(ap1, bv1, o4[nb2], 0, 0, 0);
        }
    } else {
        bf16x8 ap0 = *(const bf16x8*)&ptw[lq * 64 + ((lg ^ (lq & 7)) << 3)];
        #pragma unroll
        for (int nb2 = 0; nb2 < 4; ++nb2) {
            const int d = nb2 * 16 + lq;
            const int g0 = ((wb >> 3) + 8 + lg) ^ (d & 15);
            const bf16x8 bv0 = *(const bf16x8*)&kvT_sh[d * 128 + (g0 << 3)];
            o4[nb2] = __builtin_amdgcn_mfma_f32_16x16x32_bf16(ap0, bv0, o4[nb2], 0, 0, 0);
        }
        // ---- half1: O-partial -> own (dead) pt region as bf16, bank-XOR'd ----
        unsigned short* ofw = ptw;       // same wave, in-order reuse after ap read
        #pragma unroll
        for (int nb2 = 0; nb2 < 4; ++nb2) {
            const int d = nb2 * 16 + lq;
            #pragma unroll
            for (int r = 0; r < 4; ++r) {
                const int q = lg * 4 + r;
                ofw[q * 64 + (d ^ (lg << 3))] = f2bf(o4[nb2][r]);
            }
        }
    }
    __syncthreads();

    // ---- half0: exact flash merge + store ----
    if (half == 0) {
        const unsigned short* ofr = &pt_sh[(4 + qg) * 16 * 64];
        float c0[4], c1[4];
        #pragma unroll
        for (int r = 0; r < 4; ++r) {
            const int q = lg * 4 + r;
            const float2 a  = mz0_sh[qg][q];
            const float2 bz = mz1_sh[qg][q];
            const float m  = fmaxf(a.x, bz.x);
            const float e0 = exp2f((a.x - m) * EXPC);
            const float e1 = exp2f((bz.x - m) * EXPC);
            const float rz = 1.0f / (e0 * a.y + e1 * bz.y);
            c0[r] = e0 * rz;
            c1[r] = e1 * rz;
        }
        #pragma unroll
        for (int nb2 = 0; nb2 < 4; ++nb2) {
            const int d = nb2 * 16 + lq;
            #pragma unroll
            for (int r = 0; r < 4; ++r) {
                const int q = lg * 4 + r;
                const float o1 = bf2f(ofr[q * 64 + (d ^ (lg << 3))]);
                out[((size_t)(b * L_ + l0 + q0 + q) * H_ + h) * HD + d]
                    = c0[r] * o4[nb2][r] + c1[r] * o1;
            }
        }
    }
}

extern "C" void kernel_launch(void* const* d_in, const int* in_sizes, int n_in,
                              void* d_out, int out_size, void* d_ws, size_t ws_size,
                              hipStream_t stream)
{
    const float* x = (const float*)d_in[0];
    float* out = (float*)d_out;
    natten1d_mfma<<<dim3(B_ * H_ * NT), dim3(512), 0, stream>>>(x, out);
}

// Round 9
// 10.615 us; speedup vs baseline: 1.0902x; 1.0902x over previous
//
#include <hip/hip_runtime.h>

#define B_ 2
#define L_ 2048
#define H_ 8
#define HD 64
#define K_ 63
#define TQ 64
#define NT (L_ / TQ)          // 32 query tiles per (b,h)
#define ROWS 128              // padded window union (126 used)
#define EXPC 0.1803368801111204f   // scale(=hd^-0.5=0.125) * log2(e)

typedef __attribute__((ext_vector_type(8))) short bf16x8;   // MFMA A/B operand
typedef __attribute__((ext_vector_type(4))) float f32x4;    // MFMA C/D operand

// packed f32x2 -> bf16x2 (RNE), single HW instruction on gfx950
__device__ inline unsigned cvt_pk_bf16(float lo, float hi) {
    unsigned r;
    asm("v_cvt_pk_bf16_f32 %0, %1, %2" : "=v"(r) : "v"(lo), "v"(hi));
    return r;
}

// LDS layouts (ushort-indexed, XOR-swizzled at 16B-group granularity):
//  kv [128 keys][64 d]   grp(8/row)  ^= (row & 7)   (S^T A(K)/B(Q) frags)
//  kvT[64 d][128 keys]   grp(16/row) ^= (d & 15)    (PV B(V) frags)
//  pt [wave][16 q][128 k] grp ^= (q & 15)           (PV A(P) frags, per-wave)
//
// d-split pipeline: the XOR swizzle maps d-half A (groups 0..3) to slots
// {0..3}^(r&7) and half B to the complement -> disjoint. QK^T chain-0 reads
// only A slots, chain-1 only B slots. So: write A, barrier, chain-0 while
// B's global loads drain, write B, barrier, chain-1.
//
// Occupancy: LDS = 48 KB -> 3 blocks/CU fit; __launch_bounds__(256,3) caps
// VGPR at ~168 so 12 waves/CU (3/SIMD) are actually resident (R7 was 2/SIMD).
//
// MFMA 16x16x32 bf16 lane maps:
//  A: row m = lane&15, k = (lane>>4)*8 + j ; B: col n = lane&15, same k
//  D: col n = lane&15, row m = (lane>>4)*4 + reg
//
// S^T trick: S^T = K.Q^T -> each lane owns one query's 24 band scores.
__global__ __launch_bounds__(256, 3) void natten1d_mfma(
    const float* __restrict__ x, float* __restrict__ out)
{
    __shared__ unsigned short kv_sh [ROWS * 64];
    __shared__ unsigned short kvT_sh[64 * ROWS];
    __shared__ unsigned short pt_sh [4 * 16 * 128];

    // Bijective XCD-chunked swizzle (512 % 8 == 0)
    const int bid = blockIdx.x;
    const int wid = (bid & 7) * (B_ * H_ * NT / 8) + (bid >> 3);
    const int bh  = wid / NT;
    const int t   = wid % NT;
    const int b   = bh / H_;
    const int h   = bh % H_;
    const int l0  = t * TQ;
    const int key_base = min(max(l0 - K_ / 2, 0), L_ - K_);
    const int qoff     = l0 - key_base;          // 0 (first tile) or 31

    const int tid = threadIdx.x;
    const int c   = tid & 7;                     // d4 within half
    const int rw  = tid >> 3;                    // 0..31 -> rows rw*4..rw*4+3

    // ---- issue ALL global loads up front (A = d 0..31, B = d 32..63) ----
    const float4* xb = (const float4*)x + (size_t)b * (L_ * H_ * HD / 4) + h * (HD / 4);
    float4 la[4], lb[4];
    #pragma unroll
    for (int rr = 0; rr < 4; ++rr) {
        const int g = key_base + rw * 4 + rr;
        const bool ok = (g < L_);
        const size_t ro = (size_t)g * (H_ * HD / 4);
        la[rr] = ok ? xb[ro + c]     : make_float4(0.f, 0.f, 0.f, 0.f);
        lb[rr] = ok ? xb[ro + c + 8] : make_float4(0.f, 0.f, 0.f, 0.f);
    }

    // ---- stage half A (kv groups {0..3}^(r&7); kvT rows d 0..31) ----
    #pragma unroll
    for (int rr = 0; rr < 4; ++rr) {
        const int r = rw * 4 + rr;
        uint2 w;
        w.x = cvt_pk_bf16(la[rr].x, la[rr].y);
        w.y = cvt_pk_bf16(la[rr].z, la[rr].w);
        *(uint2*)&kv_sh[r * 64 + (((c >> 1) ^ (r & 7)) << 3) + (c & 1) * 4] = w;
    }
    {
        const int key = rw * 4;
        const float* f0 = (const float*)&la[0];
        const float* f1 = (const float*)&la[1];
        const float* f2 = (const float*)&la[2];
        const float* f3 = (const float*)&la[3];
        #pragma unroll
        for (int e = 0; e < 4; ++e) {
            const int d = c * 4 + e;
            uint2 w;
            w.x = cvt_pk_bf16(f0[e], f1[e]);
            w.y = cvt_pk_bf16(f2[e], f3[e]);
            *(uint2*)&kvT_sh[d * 128 + (((key >> 3) ^ (d & 15)) << 3) + (key & 7)] = w;
        }
    }
    __syncthreads();

    const int wave = tid >> 6;
    const int lane = tid & 63;
    const int lq = lane & 15;
    const int lg = lane >> 4;

    // ---- per-wave 96-key band window ----
    const int q0    = wave * 16;
    const int soff0 = min(max(l0 + q0 - K_ / 2, 0), L_ - K_) - key_base;
    const int wb    = min(soff0 & ~15, ROWS - 96);
    const int qrow  = qoff + q0 + lq;
    const int soffq = min(max(l0 + q0 + lq - K_ / 2, 0), L_ - K_) - key_base;
    const int cbase = wb + lg * 4 - soffq;       // mask helper

    // ---- S^T chain-0: d 0..31 only ----
    f32x4 acc[6];
    #pragma unroll
    for (int nb = 0; nb < 6; ++nb) acc[nb] = (f32x4){0.f, 0.f, 0.f, 0.f};
    {
        const bf16x8 bq0 = *(const bf16x8*)&kv_sh[qrow * 64 + ((lg ^ (qrow & 7)) << 3)];
        #pragma unroll
        for (int nb = 0; nb < 6; ++nb) {
            const int krow = wb + nb * 16 + lq;
            const bf16x8 a0 = *(const bf16x8*)&kv_sh[krow * 64 + ((lg ^ (krow & 7)) << 3)];
            acc[nb] = __builtin_amdgcn_mfma_f32_16x16x32_bf16(a0, bq0, acc[nb], 0, 0, 0);
        }
    }

    // ---- stage half B (disjoint slots; B loads drained under chain-0) ----
    #pragma unroll
    for (int rr = 0; rr < 4; ++rr) {
        const int r = rw * 4 + rr;
        uint2 w;
        w.x = cvt_pk_bf16(lb[rr].x, lb[rr].y);
        w.y = cvt_pk_bf16(lb[rr].z, lb[rr].w);
        *(uint2*)&kv_sh[r * 64 + ((((c >> 1) + 4) ^ (r & 7)) << 3) + (c & 1) * 4] = w;
    }
    {
        const int key = rw * 4;
        const float* f0 = (const float*)&lb[0];
        const float* f1 = (const float*)&lb[1];
        const float* f2 = (const float*)&lb[2];
        const float* f3 = (const float*)&lb[3];
        #pragma unroll
        for (int e = 0; e < 4; ++e) {
            const int d = 32 + c * 4 + e;
            uint2 w;
            w.x = cvt_pk_bf16(f0[e], f1[e]);
            w.y = cvt_pk_bf16(f2[e], f3[e]);
            *(uint2*)&kvT_sh[d * 128 + (((key >> 3) ^ (d & 15)) << 3) + (key & 7)] = w;
        }
    }
    __syncthreads();

    // ---- S^T chain-1: d 32..63 ----
    {
        const bf16x8 bq1 = *(const bf16x8*)&kv_sh[qrow * 64 + (((4 + lg) ^ (qrow & 7)) << 3)];
        #pragma unroll
        for (int nb = 0; nb < 6; ++nb) {
            const int krow = wb + nb * 16 + lq;
            const bf16x8 a1 = *(const bf16x8*)&kv_sh[krow * 64 + (((4 + lg) ^ (krow & 7)) << 3)];
            acc[nb] = __builtin_amdgcn_mfma_f32_16x16x32_bf16(a1, bq1, acc[nb], 0, 0, 0);
        }
    }

    // ---- per-lane softmax (one query per lane; 2 shfl per reduce) ----
    float mx = -1e30f;
    #pragma unroll
    for (int nb = 0; nb < 6; ++nb) {
        #pragma unroll
        for (int r = 0; r < 4; ++r) {
            const bool valid = (unsigned)(cbase + nb * 16 + r) < (unsigned)K_;
            const float s = valid ? acc[nb][r] : -1e30f;
            acc[nb][r] = s;
            mx = fmaxf(mx, s);
        }
    }
    mx = fmaxf(mx, __shfl_xor(mx, 16));
    mx = fmaxf(mx, __shfl_xor(mx, 32));
    float z = 0.f;
    #pragma unroll
    for (int nb = 0; nb < 6; ++nb) {
        #pragma unroll
        for (int r = 0; r < 4; ++r) {
            const float e = exp2f((acc[nb][r] - mx) * EXPC);
            acc[nb][r] = e;
            z += e;
        }
    }
    z += __shfl_xor(z, 16);
    z += __shfl_xor(z, 32);
    const float rz = 1.0f / z;

    // ---- normalized P -> per-wave pt tile (b64 writes; key-quads lane-local) ----
    unsigned short* ptw = &pt_sh[wave * 16 * 128];
    #pragma unroll
    for (int nb = 0; nb < 6; ++nb) {
        uint2 w;
        w.x = cvt_pk_bf16(acc[nb][0] * rz, acc[nb][1] * rz);
        w.y = cvt_pk_bf16(acc[nb][2] * rz, acc[nb][3] * rz);
        const int g = nb * 2 + (lg >> 1);
        *(uint2*)&ptw[lq * 128 + ((g ^ lq) << 3) + ((lg & 1) << 2)] = w;
    }

    // ---- O = P * V over the 96-key band ----
    bf16x8 ap[3];
    #pragma unroll
    for (int kc = 0; kc < 3; ++kc)
        ap[kc] = *(const bf16x8*)&ptw[lq * 128 + (((kc * 4 + lg) ^ lq) << 3)];
    f32x4 o4[4];
    #pragma unroll
    for (int nb = 0; nb < 4; ++nb) o4[nb] = (f32x4){0.f, 0.f, 0.f, 0.f};
    const int kg0 = wb >> 3;
    #pragma unroll
    for (int nb = 0; nb < 4; ++nb) {
        const int d = nb * 16 + lq;
        #pragma unroll
        for (int kc = 0; kc < 3; ++kc) {
            const bf16x8 bv =
                *(const bf16x8*)&kvT_sh[d * 128 + (((kg0 + kc * 4 + lg) ^ (d & 15)) << 3)];
            o4[nb] = __builtin_amdgcn_mfma_f32_16x16x32_bf16(ap[kc], bv, o4[nb], 0, 0, 0);
        }
    }

    // ---- epilogue: store fp32 (already normalized) ----
    #pragma unroll
    for (int nb = 0; nb < 4; ++nb) {
        const int d = nb * 16 + lq;
        #pragma unroll
        for (int r = 0; r < 4; ++r) {
            const int q = q0 + lg * 4 + r;
            out[((size_t)(b * L_ + l0 + q) * H_ + h) * HD + d] = o4[nb][r];
        }
    }
}

extern "C" void kernel_launch(void* const* d_in, const int* in_sizes, int n_in,
                              void* d_out, int out_size, void* d_ws, size_t ws_size,
                              hipStream_t stream)
{
    const float* x = (const float*)d_in[0];
    float* out = (float*)d_out;
    natten1d_mfma<<<dim3(B_ * H_ * NT), dim3(256), 0, stream>>>(x, out);
}